// Round 2
// baseline (222.432 us; speedup 1.0000x reference)
//
#include <hip/hip_runtime.h>
#include <hip/hip_bf16.h>

// out[b, i*E + j] = x[b, i] * W[i, j]
// B=8192, L=100, E=64 -> 209.7 MB fp32 output, write-streaming bound.
//
// Round-2 structure: one block per batch row b. Block = 320 threads (5 waves),
// each thread stores 5 float4s -> 1600 float4 = the whole 6400-float row,
// fully coalesced (lane-contiguous vec4 indices each iteration).
//   r = k*320 + t, i = r>>4 : W vec4 index == r (W row-major, E=64 = 16 vec4)
// W (25.6 KB) is L1-resident after first touch; x row (400 B) L1-broadcast.
// Output uses nontemporal stores: written once, never read, >> L2 capacity.

#define LENGTH 100
#define EMBED 64
#define BATCH 8192
#define V4_PER_ROW (LENGTH * EMBED / 4)   // 1600
#define TPB 320                            // 5 waves; 1600/320 = 5 exact iters

typedef float vfloat4 __attribute__((ext_vector_type(4)));

__global__ __launch_bounds__(TPB) void chemical_embedding_kernel(
    const float* __restrict__ x,
    const float* __restrict__ W,
    float* __restrict__ out)
{
    const int b = blockIdx.x;
    const int t = threadIdx.x;

    const vfloat4* __restrict__ W4 = reinterpret_cast<const vfloat4*>(W);
    const float*   __restrict__ xrow = x + b * LENGTH;
    vfloat4*       __restrict__ orow = reinterpret_cast<vfloat4*>(out) + b * V4_PER_ROW;

#pragma unroll
    for (int k = 0; k < V4_PER_ROW / TPB; ++k) {
        const int r = k * TPB + t;
        const float s = xrow[r >> 4];     // 16 lanes share one x scalar (L1 broadcast)
        vfloat4 w = W4[r];                // coalesced, L1-resident (25.6 KB table)
        vfloat4 o = s * w;
        __builtin_nontemporal_store(o, &orow[r]);
    }
}

extern "C" void kernel_launch(void* const* d_in, const int* in_sizes, int n_in,
                              void* d_out, int out_size, void* d_ws, size_t ws_size,
                              hipStream_t stream) {
    const float* x = (const float*)d_in[0];
    const float* W = (const float*)d_in[1];
    float* out = (float*)d_out;

    chemical_embedding_kernel<<<BATCH, TPB, 0, stream>>>(x, W, out);
}

// Round 3
// 205.452 us; speedup vs baseline: 1.0826x; 1.0826x over previous
//
#include <hip/hip_runtime.h>
#include <hip/hip_bf16.h>

// out[b, i*E + j] = x[b, i] * W[i, j]
// B=8192, L=100, E=64 -> 209.7 MB fp32 output, pure write-streaming bound.
//
// Round-3 structure: thread owns a FIXED output column (vec4 index r in
// [0,1600)), loads its W vec4 ONCE into registers, then strides over batch
// rows. Inner loop = 1 scalar x-load (broadcast across 16 lanes, L2-resident)
// + 4 muls + 1 coalesced 16B store. This matches the structure of the
// harness fill kernel (long independent store streams) which demonstrates
// 6.8 TB/s on this same buffer.
//
// Grid: x-dim 5 blocks x 320 threads cover all 1600 columns;
//       y-dim 256 slices of the batch -> 32 iterations/thread.
// 1280 blocks x 5 waves = 6400 waves = 25 waves/CU: plenty of stores in
// flight, W-load fully amortized.

#define LENGTH 100
#define EMBED 64
#define BATCH 8192
#define V4_PER_ROW (LENGTH * EMBED / 4)   // 1600
#define TPB 320                            // 5 waves; 5 blocks cover 1600 cols
#define BSLICES 256                        // batch slices; 8192/256 = 32 iters

typedef float vfloat4 __attribute__((ext_vector_type(4)));

__global__ __launch_bounds__(TPB) void chemical_embedding_kernel(
    const float* __restrict__ x,
    const float* __restrict__ W,
    float* __restrict__ out)
{
    const int r = blockIdx.x * TPB + threadIdx.x;   // vec4 column, [0,1600)
    const int i = r >> 4;                            // L index (E/4 = 16 vec4/i)

    // Loop-invariant: this thread's W fragment, loaded once.
    const vfloat4 w = reinterpret_cast<const vfloat4*>(W)[r];

    const int b0 = blockIdx.y;                       // starting batch row
    const float* __restrict__ xp = x + b0 * LENGTH + i;
    vfloat4* __restrict__ op =
        reinterpret_cast<vfloat4*>(out) + (size_t)b0 * V4_PER_ROW + r;

    const int xstep = BSLICES * LENGTH;              // x ptr bump per iter
    const int ostep = BSLICES * V4_PER_ROW;          // out ptr bump per iter

#pragma unroll 4
    for (int it = 0; it < BATCH / BSLICES; ++it) {   // 32 iterations
        const float s = *xp;                         // 4B, L2-resident, 16-lane share
        *op = s * w;                                 // coalesced 16B store
        xp += xstep;
        op += ostep;
    }
}

extern "C" void kernel_launch(void* const* d_in, const int* in_sizes, int n_in,
                              void* d_out, int out_size, void* d_ws, size_t ws_size,
                              hipStream_t stream) {
    const float* x = (const float*)d_in[0];
    const float* W = (const float*)d_in[1];
    float* out = (float*)d_out;

    dim3 grid(V4_PER_ROW / TPB, BSLICES);            // (5, 256) = 1280 blocks
    chemical_embedding_kernel<<<grid, TPB, 0, stream>>>(x, W, out);
}